// Round 1
// baseline (1735.631 us; speedup 1.0000x reference)
//
#include <hip/hip_runtime.h>
#include <math.h>

#define QD 6
#define LTC 10
#define NW 8192
#define NT (NW + LTC)      // 8202
#define D60 60
#define MI 256
#define JITTER 1e-6f

// ws layout (float offsets)
#define OFF_W      0                       // 8192*64
#define OFF_SLOG   524288                  // 8192*256
#define OFF_ACC    (OFF_SLOG + 2097152)    // 65536
#define OFF_KUU    (OFF_ACC + 65536)
#define OFF_G      (OFF_KUU + 65536)
#define OFF_PSI2   (OFF_G + 65536)
#define OFF_RPART  (OFF_PSI2 + 65536)      // 512*256*6
#define OFF_R      (OFF_RPART + 786432)    // 1536
#define OFF_SCAL   (OFF_R + 1536)          // 16
// scal: 0 sumXvo, 1 sumXmo2, 2 sumlogXvo, 3 summb, 4 trace_raw, 5 ldK, 6 ldG

__global__ __launch_bounds__(256) void k_reduce_x(const float* __restrict__ Xm,
                                                  const float* __restrict__ Xv,
                                                  float* __restrict__ scal) {
    float s0 = 0.f, s1 = 0.f, s2 = 0.f, s3 = 0.f;
    const int tot = NT * QD;
    for (int i = blockIdx.x * blockDim.x + threadIdx.x; i < tot; i += gridDim.x * blockDim.x) {
        float xm = Xm[i], xv = Xv[i];
        if (i >= LTC * QD) { s0 += xv; s1 += xm * xm; s2 += __logf(xv); }
        else { s3 += xm * xm + xv; }
    }
    #pragma unroll
    for (int o = 32; o; o >>= 1) {
        s0 += __shfl_down(s0, o); s1 += __shfl_down(s1, o);
        s2 += __shfl_down(s2, o); s3 += __shfl_down(s3, o);
    }
    __shared__ float red[4][4];
    const int t = threadIdx.x;
    if ((t & 63) == 0) { int w = t >> 6; red[0][w] = s0; red[1][w] = s1; red[2][w] = s2; red[3][w] = s3; }
    __syncthreads();
    if (t == 0) {
        float a0 = 0, a1 = 0, a2 = 0, a3 = 0;
        for (int w = 0; w < 4; ++w) { a0 += red[0][w]; a1 += red[1][w]; a2 += red[2][w]; a3 += red[3][w]; }
        unsafeAtomicAdd(&scal[0], a0); unsafeAtomicAdd(&scal[1], a1);
        unsafeAtomicAdd(&scal[2], a2); unsafeAtomicAdd(&scal[3], a3);
    }
}

// prep: per-n w, Slog (log of separable psi2 factor), psi1^T X_mo partials
__global__ __launch_bounds__(256) void k_prep(const float* __restrict__ Xm, const float* __restrict__ Xv,
                                              const float* __restrict__ Zg, const float* __restrict__ kvar,
                                              const float* __restrict__ klen,
                                              float* __restrict__ W, float* __restrict__ Slog,
                                              float* __restrict__ rpart) {
    __shared__ float Zt[D60][MI];
    __shared__ float4 quad[D60];   // {w*mu, w, 1/(S+l2), mu}
    __shared__ float ldsm[66];
    __shared__ float ldss[60];
    __shared__ float sld[2];       // 0: ld1, 1: base=0.5*(ld2-e1)
    const int t = threadIdx.x;
    const float sf2 = kvar[0];
    const float l = klen[0];
    const float l2 = l * l;
    for (int idx = t; idx < D60 * MI; idx += 256) {
        int d = idx >> 8, m = idx & 255;
        Zt[d][m] = Zg[m * D60 + d];
    }
    float r6[QD];
    #pragma unroll
    for (int q = 0; q < QD; ++q) r6[q] = 0.f;
    const int n0 = blockIdx.x * 16;
    for (int nn = 0; nn < 16; ++nn) {
        const int n = n0 + nn;
        __syncthreads();
        if (t < 66) ldsm[t] = Xm[n * QD + t];
        if (t >= 128 && t < 188) ldss[t - 128] = Xv[n * QD + (t - 128)];
        __syncthreads();
        if (t < 64) {
            float lt1 = 0.f, lt2 = 0.f, e1t = 0.f;
            if (t < 60) {
                float S = ldss[t], mu = ldsm[t];
                float w = 1.0f / (2.0f * S + l2);
                float invd1 = 1.0f / (S + l2);
                quad[t] = make_float4(w * mu, w, invd1, mu);
                W[n * 64 + t] = w;
                lt1 = __logf(1.0f + S / l2);
                lt2 = __logf(1.0f + 2.0f * S / l2);
                e1t = w * mu * mu;
            }
            #pragma unroll
            for (int o = 32; o; o >>= 1) {
                lt1 += __shfl_down(lt1, o); lt2 += __shfl_down(lt2, o); e1t += __shfl_down(e1t, o);
            }
            if (t == 0) { sld[0] = -0.5f * lt1; sld[1] = 0.5f * (-0.5f * lt2 - e1t); }
        }
        __syncthreads();
        float e2 = 0.f, e3 = 0.f, q1 = 0.f;
        #pragma unroll 10
        for (int d = 0; d < D60; ++d) {
            float4 qd = quad[d];
            float z = Zt[d][t];
            e2 += qd.x * z;
            e3 += qd.y * z * z;
            float dm = qd.w - z;
            q1 += dm * dm * qd.z;
        }
        Slog[n * MI + t] = sld[1] + e2 - 0.25f * e3;
        float psi1 = sf2 * __expf(sld[0] - 0.5f * q1);
        #pragma unroll
        for (int q = 0; q < QD; ++q) r6[q] += psi1 * ldsm[60 + q];
    }
    #pragma unroll
    for (int q = 0; q < QD; ++q) rpart[(blockIdx.x * MI + t) * QD + q] = r6[q];
}

// main: acc[m,p] += sum_n exp(s[n,m]+s[n,p]-e4)
__global__ __launch_bounds__(256, 2) void k_acc(const float* __restrict__ Zg, const float* __restrict__ W,
                                                const float* __restrict__ Slog, float* __restrict__ acc) {
    __shared__ float Za[D60][128];
    __shared__ float Zb[D60][128];
    __shared__ float wbuf[D60];
    __shared__ float sa[128], sb[128];
    const int t = threadIdx.x;
    const int tile = blockIdx.x & 3;
    const int nc = blockIdx.x >> 2;        // 0..127
    const int m0 = (tile >> 1) * 128, p0 = (tile & 1) * 128;
    const int tx = t & 15, ty = t >> 4;
    for (int idx = t; idx < 128 * D60; idx += 256) {
        int d = idx >> 7, mi = idx & 127;
        Za[d][mi] = Zg[(m0 + mi) * D60 + d];
        Zb[d][mi] = Zg[(p0 + mi) * D60 + d];
    }
    float accr[8][8];
    #pragma unroll
    for (int i = 0; i < 8; ++i)
        #pragma unroll
        for (int j = 0; j < 8; ++j) accr[i][j] = 0.f;
    const int n0 = nc * 64;
    for (int nn = 0; nn < 64; ++nn) {
        const int n = n0 + nn;
        __syncthreads();
        if (t < D60) wbuf[t] = 0.5f * W[n * 64 + t];
        if (t < 128) sa[t] = Slog[n * MI + m0 + t];
        else sb[t - 128] = Slog[n * MI + p0 + (t - 128)];
        __syncthreads();
        float E[8][8];
        #pragma unroll
        for (int i = 0; i < 8; ++i)
            #pragma unroll
            for (int j = 0; j < 8; ++j) E[i][j] = 0.f;
        #pragma unroll 4
        for (int d = 0; d < D60; ++d) {
            const float wd = wbuf[d];
            const float4 A0 = *(const float4*)(&Za[d][ty * 4]);
            const float4 A1 = *(const float4*)(&Za[d][64 + ty * 4]);
            const float4 B0 = *(const float4*)(&Zb[d][tx * 4]);
            const float4 B1 = *(const float4*)(&Zb[d][64 + tx * 4]);
            float a[8] = {A0.x * wd, A0.y * wd, A0.z * wd, A0.w * wd,
                          A1.x * wd, A1.y * wd, A1.z * wd, A1.w * wd};
            float b[8] = {B0.x, B0.y, B0.z, B0.w, B1.x, B1.y, B1.z, B1.w};
            #pragma unroll
            for (int i = 0; i < 8; ++i)
                #pragma unroll
                for (int j = 0; j < 8; ++j) E[i][j] += a[i] * b[j];
        }
        float sav[8], sbv[8];
        #pragma unroll
        for (int i = 0; i < 8; ++i) {
            sav[i] = sa[(i < 4) ? (ty * 4 + i) : (64 + ty * 4 + i - 4)];
            sbv[i] = sb[(i < 4) ? (tx * 4 + i) : (64 + tx * 4 + i - 4)];
        }
        #pragma unroll
        for (int i = 0; i < 8; ++i)
            #pragma unroll
            for (int j = 0; j < 8; ++j)
                accr[i][j] += __expf(sav[i] + sbv[j] - E[i][j]);
    }
    #pragma unroll
    for (int i = 0; i < 8; ++i) {
        int mi = (i < 4) ? (ty * 4 + i) : (64 + ty * 4 + i - 4);
        #pragma unroll
        for (int j = 0; j < 8; ++j) {
            int pj = (j < 4) ? (tx * 4 + j) : (64 + tx * 4 + j - 4);
            unsafeAtomicAdd(&acc[(m0 + mi) * MI + (p0 + pj)], accr[i][j]);
        }
    }
}

__global__ __launch_bounds__(256) void k_psi2(const float* __restrict__ Zg, const float* __restrict__ kvar,
                                              const float* __restrict__ klen, const float* __restrict__ lvar,
                                              const float* __restrict__ acc, float* __restrict__ psi2,
                                              float* __restrict__ Kuu, float* __restrict__ G) {
    __shared__ float zi[D60];
    const int i = blockIdx.x, j = threadIdx.x;
    if (j < D60) zi[j] = Zg[i * D60 + j];
    __syncthreads();
    const float sf2 = kvar[0];
    const float l = klen[0];
    const float l2 = l * l;
    const float sigma2 = lvar[0];
    float zz = 0.f;
    #pragma unroll 10
    for (int d = 0; d < D60; ++d) {
        float dz = zi[d] - Zg[j * D60 + d];
        zz += dz * dz;
    }
    float accv = acc[i * MI + j];
    float p2 = sf2 * sf2 * __expf(-zz / (4.f * l2)) * accv;
    psi2[i * MI + j] = p2;
    float kv = sf2 * __expf(-0.5f * zz / l2) + ((i == j) ? JITTER : 0.f);
    Kuu[i * MI + j] = kv;
    G[i * MI + j] = kv + p2 / sigma2;
}

__global__ void k_reduce_r(const float* __restrict__ rpart, float* __restrict__ r) {
    int idx = blockIdx.x * blockDim.x + threadIdx.x;   // 0..1535
    float s = 0.f;
    for (int b = 0; b < 512; ++b) s += rpart[b * 1536 + idx];
    r[idx] = s;
}

// single-block panel Cholesky (in-place lower), writes 2*sum(log diag)
__global__ __launch_bounds__(1024) void k_chol(float* __restrict__ A, float* __restrict__ ldout) {
    __shared__ float Pt[32][MI];   // Pt[c][r] = A[p+r][p+c]
    __shared__ float red[16];
    const int t = threadIdx.x;
    for (int p = 0; p < MI; p += 32) {
        const int R = MI - p;
        for (int idx = t; idx < R * 32; idx += 1024) {
            int c = idx / R, rr = idx % R;
            Pt[c][rr] = A[(p + rr) * MI + (p + c)];
        }
        __syncthreads();
        for (int jj = 0; jj < 32; ++jj) {
            float dg = sqrtf(Pt[jj][jj]);
            float inv = 1.0f / dg;
            for (int rr = jj + 1 + t; rr < R; rr += 1024) Pt[jj][rr] *= inv;
            if (t == 0) Pt[jj][jj] = dg;
            __syncthreads();
            int ncols = 31 - jj;
            if (ncols > 0) {
                int rows = R - jj - 1;
                for (int idx = t; idx < rows * ncols; idx += 1024) {
                    int c = jj + 1 + idx / rows;
                    int rr = jj + 1 + idx % rows;
                    Pt[c][rr] -= Pt[jj][rr] * Pt[jj][c];
                }
            }
            __syncthreads();
        }
        for (int idx = t; idx < R * 32; idx += 1024) {
            int c = idx / R, rr = idx % R;
            A[(p + rr) * MI + (p + c)] = Pt[c][rr];
        }
        const int T = R - 32;
        if (T > 0) {
            const int BT = T >> 2;
            const int nb = BT * (BT + 1) / 2;
            for (int b = t; b < nb; b += 1024) {
                int br = (int)((sqrtf(8.0f * b + 1.0f) - 1.0f) * 0.5f);
                while ((br + 1) * (br + 2) / 2 <= b) ++br;
                while (br * (br + 1) / 2 > b) --br;
                int bc = b - br * (br + 1) / 2;
                int r0 = 32 + br * 4, c0 = 32 + bc * 4;
                float s[4][4];
                #pragma unroll
                for (int i = 0; i < 4; ++i)
                    #pragma unroll
                    for (int j = 0; j < 4; ++j) s[i][j] = 0.f;
                #pragma unroll 8
                for (int kk = 0; kk < 32; ++kk) {
                    float4 av = *(const float4*)(&Pt[kk][r0]);
                    float4 bv = *(const float4*)(&Pt[kk][c0]);
                    float aa[4] = {av.x, av.y, av.z, av.w};
                    float bb[4] = {bv.x, bv.y, bv.z, bv.w};
                    #pragma unroll
                    for (int i = 0; i < 4; ++i)
                        #pragma unroll
                        for (int j = 0; j < 4; ++j) s[i][j] += aa[i] * bb[j];
                }
                #pragma unroll
                for (int i = 0; i < 4; ++i)
                    #pragma unroll
                    for (int j = 0; j < 4; ++j)
                        A[(p + r0 + i) * MI + (p + c0 + j)] -= s[i][j];
            }
        }
        __syncthreads();
    }
    float lg = 0.f;
    if (t < MI) lg = __logf(A[t * MI + t]);
    #pragma unroll
    for (int o = 32; o; o >>= 1) lg += __shfl_down(lg, o);
    if ((t & 63) == 0) red[t >> 6] = lg;
    __syncthreads();
    if (t == 0) {
        float s = 0.f;
        for (int k = 0; k < 16; ++k) s += red[k];
        ldout[0] = 2.0f * s;
    }
}

// trace(Kuu^{-1} psi2): block j solves Kuu x = psi2[:,j], adds x[j]
__global__ __launch_bounds__(256) void k_trace(const float* __restrict__ L, const float* __restrict__ psi2,
                                               float* __restrict__ scal) {
    __shared__ float xsh[MI];
    const int t = threadIdx.x;
    const int j = blockIdx.x;
    float x = psi2[t * MI + j];
    for (int i = 0; i < MI; ++i) {
        if (t == i) { x /= L[i * MI + i]; xsh[i] = x; }
        __syncthreads();
        if (t > i) x -= L[t * MI + i] * xsh[i];
    }
    __syncthreads();
    for (int i = MI - 1; i >= 0; --i) {
        if (t == i) { x /= L[i * MI + i]; xsh[i] = x; }
        __syncthreads();
        if (t < i) x -= L[i * MI + t] * xsh[i];
    }
    if (t == j) unsafeAtomicAdd(&scal[4], x);
}

// solve G y = r (6 rhs), csum = sum(y .* r), assemble final bound
__global__ __launch_bounds__(256) void k_rsolve_final(const float* __restrict__ LG, const float* __restrict__ r,
                                                      const float* __restrict__ scal,
                                                      const float* __restrict__ kvar, const float* __restrict__ klen,
                                                      const float* __restrict__ lvar, const int* __restrict__ ltp,
                                                      float* __restrict__ out) {
    __shared__ float xf[MI][QD];
    __shared__ float xb[MI][QD];
    __shared__ float red[4];
    const int t = threadIdx.x;
    float x[QD];
    #pragma unroll
    for (int q = 0; q < QD; ++q) x[q] = r[t * QD + q];
    for (int i = 0; i < MI; ++i) {
        if (t == i) {
            float inv = 1.0f / LG[i * MI + i];
            #pragma unroll
            for (int q = 0; q < QD; ++q) { x[q] *= inv; xf[i][q] = x[q]; }
        }
        __syncthreads();
        if (t > i) {
            float lv = LG[t * MI + i];
            #pragma unroll
            for (int q = 0; q < QD; ++q) x[q] -= lv * xf[i][q];
        }
    }
    __syncthreads();
    for (int i = MI - 1; i >= 0; --i) {
        if (t == i) {
            float inv = 1.0f / LG[i * MI + i];
            #pragma unroll
            for (int q = 0; q < QD; ++q) { x[q] *= inv; xb[i][q] = x[q]; }
        }
        __syncthreads();
        if (t < i) {
            float lv = LG[i * MI + t];
            #pragma unroll
            for (int q = 0; q < QD; ++q) x[q] -= lv * xb[i][q];
        }
    }
    float cs = 0.f;
    #pragma unroll
    for (int q = 0; q < QD; ++q) cs += x[q] * r[t * QD + q];
    #pragma unroll
    for (int o = 32; o; o >>= 1) cs += __shfl_down(cs, o);
    if ((t & 63) == 0) red[t >> 6] = cs;
    __syncthreads();
    if (t == 0) {
        double csum = (double)red[0] + red[1] + red[2] + red[3];
        double sigma2 = (double)lvar[0];
        double sf2 = (double)kvar[0];
        (void)klen;
        double two_pi = 6.283185307179586;
        double Nw = (double)NW, Q = (double)QD;
        double psi0 = Nw * sf2;
        double trace_AAT = (double)scal[4] / sigma2;
        double logdetB = (double)scal[6] - (double)scal[5];
        double bound = -0.5 * Nw * Q * log(two_pi * sigma2);
        bound += -0.5 / sigma2 * ((double)scal[0] + (double)scal[1]);
        bound += -0.5 * Q * (psi0 / sigma2 - trace_AAT);
        bound += -0.5 * Q * logdetB;
        bound += 0.5 * csum / (sigma2 * sigma2);
        bound += 0.5 * (double)scal[2] + Nw * Q * 0.5 * log(two_pi);
        bound += -(double)ltp[0] * Q * log(two_pi) - 0.5 * (double)scal[3];
        out[0] = (float)bound;
    }
}

extern "C" void kernel_launch(void* const* d_in, const int* in_sizes, int n_in,
                              void* d_out, int out_size, void* d_ws, size_t ws_size,
                              hipStream_t stream) {
    (void)in_sizes; (void)n_in; (void)out_size; (void)ws_size;
    const float* Xm = (const float*)d_in[0];
    const float* Xv = (const float*)d_in[1];
    const float* Zg = (const float*)d_in[2];
    const float* kvar = (const float*)d_in[3];
    const float* klen = (const float*)d_in[4];
    const float* lvar = (const float*)d_in[5];
    const int* ltp = (const int*)d_in[6];
    float* ws = (float*)d_ws;
    float* W = ws + OFF_W;
    float* Slog = ws + OFF_SLOG;
    float* acc = ws + OFF_ACC;
    float* Kuu = ws + OFF_KUU;
    float* G = ws + OFF_G;
    float* psi2 = ws + OFF_PSI2;
    float* rpart = ws + OFF_RPART;
    float* r = ws + OFF_R;
    float* scal = ws + OFF_SCAL;

    hipMemsetAsync(acc, 0, MI * MI * sizeof(float), stream);
    hipMemsetAsync(scal, 0, 16 * sizeof(float), stream);

    k_reduce_x<<<64, 256, 0, stream>>>(Xm, Xv, scal);
    k_prep<<<512, 256, 0, stream>>>(Xm, Xv, Zg, kvar, klen, W, Slog, rpart);
    k_acc<<<512, 256, 0, stream>>>(Zg, W, Slog, acc);
    k_psi2<<<256, 256, 0, stream>>>(Zg, kvar, klen, lvar, acc, psi2, Kuu, G);
    k_reduce_r<<<6, 256, 0, stream>>>(rpart, r);
    k_chol<<<1, 1024, 0, stream>>>(Kuu, scal + 5);
    k_chol<<<1, 1024, 0, stream>>>(G, scal + 6);
    k_trace<<<256, 256, 0, stream>>>(Kuu, psi2, scal);
    k_rsolve_final<<<1, 256, 0, stream>>>(G, r, scal, kvar, klen, lvar, ltp, (float*)d_out);
}

// Round 3
// 1303.498 us; speedup vs baseline: 1.3315x; 1.3315x over previous
//
#include <hip/hip_runtime.h>
#include <math.h>

#define QD 6
#define LTC 10
#define NW 8192
#define NT (NW + LTC)      // 8202
#define D60 60
#define MI 256
#define JITTER 1e-6f
#define LOG2E 1.4426950408889634f

typedef __attribute__((ext_vector_type(8))) short bf16x8;
typedef __attribute__((ext_vector_type(4))) float f32x4;

// ws layout (float offsets)
#define OFF_W      0                       // 8192*64
#define OFF_SLOG   524288                  // 8192*256
#define OFF_ACC    (OFF_SLOG + 2097152)    // 65536
#define OFF_KUU    (OFF_ACC + 65536)
#define OFF_G      (OFF_KUU + 65536)
#define OFF_PSI2   (OFF_G + 65536)
#define OFF_RPART  (OFF_PSI2 + 65536)      // 512*256*6
#define OFF_R      (OFF_RPART + 786432)    // 1536
#define OFF_SCAL   (OFF_R + 1536)          // 16
#define OFF_TI1    (OFF_SCAL + 16)         // 65536
#define OFF_TI2    (OFF_TI1 + 65536)       // 65536
// scal: 0 sumXvo, 1 sumXmo2, 2 sumlogXvo, 3 summb, 4 trace_raw, 5 ldK, 6 ldG

__device__ __forceinline__ ushort f2bf(float f) {
    union { float f; unsigned u; } x; x.f = f;
    unsigned r = x.u + 0x7fffu + ((x.u >> 16) & 1u);
    return (ushort)(r >> 16);
}
__device__ __forceinline__ float bf2f(ushort h) {
    return __uint_as_float(((unsigned)h) << 16);
}

__global__ __launch_bounds__(256) void k_reduce_x(const float* __restrict__ Xm,
                                                  const float* __restrict__ Xv,
                                                  float* __restrict__ scal) {
    float s0 = 0.f, s1 = 0.f, s2 = 0.f, s3 = 0.f;
    const int tot = NT * QD;
    for (int i = blockIdx.x * blockDim.x + threadIdx.x; i < tot; i += gridDim.x * blockDim.x) {
        float xm = Xm[i], xv = Xv[i];
        if (i >= LTC * QD) { s0 += xv; s1 += xm * xm; s2 += __logf(xv); }
        else { s3 += xm * xm + xv; }
    }
    #pragma unroll
    for (int o = 32; o; o >>= 1) {
        s0 += __shfl_down(s0, o); s1 += __shfl_down(s1, o);
        s2 += __shfl_down(s2, o); s3 += __shfl_down(s3, o);
    }
    __shared__ float red[4][4];
    const int t = threadIdx.x;
    if ((t & 63) == 0) { int w = t >> 6; red[0][w] = s0; red[1][w] = s1; red[2][w] = s2; red[3][w] = s3; }
    __syncthreads();
    if (t == 0) {
        float a0 = 0, a1 = 0, a2 = 0, a3 = 0;
        for (int w = 0; w < 4; ++w) { a0 += red[0][w]; a1 += red[1][w]; a2 += red[2][w]; a3 += red[3][w]; }
        unsafeAtomicAdd(&scal[0], a0); unsafeAtomicAdd(&scal[1], a1);
        unsafeAtomicAdd(&scal[2], a2); unsafeAtomicAdd(&scal[3], a3);
    }
}

// prep: per-n scaled w (-0.5*log2e*w, zeros at 60..63), Slog, psi1^T X_mo partials
__global__ __launch_bounds__(256) void k_prep(const float* __restrict__ Xm, const float* __restrict__ Xv,
                                              const float* __restrict__ Zg, const float* __restrict__ kvar,
                                              const float* __restrict__ klen,
                                              float* __restrict__ W, float* __restrict__ Slog,
                                              float* __restrict__ rpart) {
    __shared__ float Zt[D60][MI];
    __shared__ float4 quad[D60];   // {w*mu, w, 1/(S+l2), mu}
    __shared__ float ldsm[66];
    __shared__ float ldss[60];
    __shared__ float sld[2];       // 0: ld1, 1: base=0.5*(ld2-e1)
    const int t = threadIdx.x;
    const float sf2 = kvar[0];
    const float l = klen[0];
    const float l2 = l * l;
    for (int idx = t; idx < D60 * MI; idx += 256) {
        int d = idx >> 8, m = idx & 255;
        Zt[d][m] = Zg[m * D60 + d];
    }
    float r6[QD];
    #pragma unroll
    for (int q = 0; q < QD; ++q) r6[q] = 0.f;
    const int n0 = blockIdx.x * 16;
    for (int nn = 0; nn < 16; ++nn) {
        const int n = n0 + nn;
        __syncthreads();
        if (t < 66) ldsm[t] = Xm[n * QD + t];
        if (t >= 128 && t < 188) ldss[t - 128] = Xv[n * QD + (t - 128)];
        __syncthreads();
        if (t < 64) {
            float lt1 = 0.f, lt2 = 0.f, e1t = 0.f;
            if (t < 60) {
                float S = ldss[t], mu = ldsm[t];
                float w = 1.0f / (2.0f * S + l2);
                float invd1 = 1.0f / (S + l2);
                quad[t] = make_float4(w * mu, w, invd1, mu);
                W[n * 64 + t] = -0.5f * LOG2E * w;
                lt1 = __logf(1.0f + S / l2);
                lt2 = __logf(1.0f + 2.0f * S / l2);
                e1t = w * mu * mu;
            } else {
                W[n * 64 + t] = 0.f;
            }
            #pragma unroll
            for (int o = 32; o; o >>= 1) {
                lt1 += __shfl_down(lt1, o); lt2 += __shfl_down(lt2, o); e1t += __shfl_down(e1t, o);
            }
            if (t == 0) { sld[0] = -0.5f * lt1; sld[1] = 0.5f * (-0.5f * lt2 - e1t); }
        }
        __syncthreads();
        float e2 = 0.f, e3 = 0.f, q1 = 0.f;
        #pragma unroll 10
        for (int d = 0; d < D60; ++d) {
            float4 qd = quad[d];
            float z = Zt[d][t];
            e2 += qd.x * z;
            e3 += qd.y * z * z;
            float dm = qd.w - z;
            q1 += dm * dm * qd.z;
        }
        Slog[n * MI + t] = sld[1] + e2 - 0.25f * e3;
        float psi1 = sf2 * __expf(sld[0] - 0.5f * q1);
        #pragma unroll
        for (int q = 0; q < QD; ++q) r6[q] += psi1 * ldsm[60 + q];
    }
    #pragma unroll
    for (int q = 0; q < QD; ++q) rpart[(blockIdx.x * MI + t) * QD + q] = r6[q];
}

// main: acc[m,p] += sum_n exp2( LOG2E*(Slog_a + Slog_b) + d ), d = -LOG2E*e4 via split-bf16 MFMA
__global__ __launch_bounds__(256, 2) void k_acc(const float* __restrict__ Zg, const float* __restrict__ W,
                                                const float* __restrict__ Slog, float* __restrict__ acc) {
    __shared__ ushort Ah[128 * 64];   // 16 KB, XOR-swizzled rows
    __shared__ ushort Al[128 * 64];   // 16 KB
    __shared__ float saa[128], sbb[128];
    const int t = threadIdx.x;
    const int tile = blockIdx.x & 3;
    const int nc = blockIdx.x >> 2;      // 0..127, 64 n each
    const int m0 = (tile >> 1) * 128, p0 = (tile & 1) * 128;
    const int lane = t & 63, wid = t >> 6;
    const int wr = wid >> 1, wc = wid & 1;
    const int sm = t & 127, kh = t >> 7;

    // persistent Z rows for A staging: zr[j] = Z[(m0+sm)][kh*32+j]
    float zr[32];
    #pragma unroll
    for (int j = 0; j < 32; ++j) {
        int k = kh * 32 + j;
        zr[j] = (k < D60) ? Zg[(m0 + sm) * D60 + k] : 0.f;
    }
    // stage B hi/lo into Ah/Al temporarily, then keep fragments in registers
    for (int idx = t; idx < 128 * 64; idx += 256) {
        int p = idx >> 6, k = idx & 63;
        float v = (k < D60) ? Zg[(p0 + p) * D60 + k] : 0.f;
        ushort hi = f2bf(v);
        ushort lo = f2bf(v - bf2f(hi));
        int byte = p * 128 + ((k * 2) ^ ((p & 7) << 4));
        *(ushort*)((char*)Ah + byte) = hi;
        *(ushort*)((char*)Al + byte) = lo;
    }
    __syncthreads();
    bf16x8 bh[4][2], bl[4][2];
    #pragma unroll
    for (int ct = 0; ct < 4; ++ct) {
        int p = 64 * wc + 16 * ct + (lane & 15);
        int swz = (p & 7) << 4;
        #pragma unroll
        for (int h = 0; h < 2; ++h) {
            int byte = p * 128 + ((((lane >> 4) * 16) + 64 * h) ^ swz);
            bh[ct][h] = *(const bf16x8*)((const char*)Ah + byte);
            bl[ct][h] = *(const bf16x8*)((const char*)Al + byte);
        }
    }

    float accr[4][4][4];
    #pragma unroll
    for (int a = 0; a < 4; ++a)
        #pragma unroll
        for (int b = 0; b < 4; ++b)
            #pragma unroll
            for (int c = 0; c < 4; ++c) accr[a][b][c] = 0.f;

    const int n0 = nc * 64;
    for (int nn = 0; nn < 64; ++nn) {
        const int n = n0 + nn;
        __syncthreads();   // previous compute done reading Ah/Al
        // ---- stage A hi/lo (a = Wscaled * z, fp32 product, split to bf16 pair) ----
        {
            const float4* wp = (const float4*)(W + n * 64 + kh * 32);
            float av[32];
            #pragma unroll
            for (int j = 0; j < 8; ++j) {
                float4 f = wp[j];
                av[4 * j + 0] = f.x * zr[4 * j + 0];
                av[4 * j + 1] = f.y * zr[4 * j + 1];
                av[4 * j + 2] = f.z * zr[4 * j + 2];
                av[4 * j + 3] = f.w * zr[4 * j + 3];
            }
            unsigned pkh[16], pkl[16];
            #pragma unroll
            for (int j = 0; j < 16; ++j) {
                float v0 = av[2 * j], v1 = av[2 * j + 1];
                ushort h0 = f2bf(v0), h1 = f2bf(v1);
                ushort l0 = f2bf(v0 - bf2f(h0)), l1 = f2bf(v1 - bf2f(h1));
                pkh[j] = (unsigned)h0 | ((unsigned)h1 << 16);
                pkl[j] = (unsigned)l0 | ((unsigned)l1 << 16);
            }
            #pragma unroll
            for (int cc = 0; cc < 4; ++cc) {
                int byte = sm * 128 + (((kh * 64) + cc * 16) ^ ((sm & 7) << 4));
                uint4 vh; vh.x = pkh[4 * cc]; vh.y = pkh[4 * cc + 1]; vh.z = pkh[4 * cc + 2]; vh.w = pkh[4 * cc + 3];
                uint4 vl; vl.x = pkl[4 * cc]; vl.y = pkl[4 * cc + 1]; vl.z = pkl[4 * cc + 2]; vl.w = pkl[4 * cc + 3];
                *(uint4*)((char*)Ah + byte) = vh;
                *(uint4*)((char*)Al + byte) = vl;
            }
            if (t < 128) saa[t] = LOG2E * Slog[n * MI + m0 + t];
            else sbb[t - 128] = LOG2E * Slog[n * MI + p0 + (t - 128)];
        }
        __syncthreads();
        // ---- compute ----
        float sbv[4];
        #pragma unroll
        for (int ct = 0; ct < 4; ++ct) sbv[ct] = sbb[64 * wc + 16 * ct + (lane & 15)];
        #pragma unroll
        for (int rt = 0; rt < 4; ++rt) {
            int m = 64 * wr + 16 * rt + (lane & 15);
            int swz = (m & 7) << 4;
            bf16x8 ah0 = *(const bf16x8*)((const char*)Ah + m * 128 + (((lane >> 4) * 16) ^ swz));
            bf16x8 ah1 = *(const bf16x8*)((const char*)Ah + m * 128 + ((64 + (lane >> 4) * 16) ^ swz));
            bf16x8 al0 = *(const bf16x8*)((const char*)Al + m * 128 + (((lane >> 4) * 16) ^ swz));
            bf16x8 al1 = *(const bf16x8*)((const char*)Al + m * 128 + ((64 + (lane >> 4) * 16) ^ swz));
            float sav[4];
            int rbase = 64 * wr + 16 * rt + (lane >> 4) * 4;
            #pragma unroll
            for (int rr = 0; rr < 4; ++rr) sav[rr] = saa[rbase + rr];
            #pragma unroll
            for (int ct = 0; ct < 4; ++ct) {
                f32x4 d = {0.f, 0.f, 0.f, 0.f};
                d = __builtin_amdgcn_mfma_f32_16x16x32_bf16(ah0, bh[ct][0], d, 0, 0, 0);
                d = __builtin_amdgcn_mfma_f32_16x16x32_bf16(ah1, bh[ct][1], d, 0, 0, 0);
                d = __builtin_amdgcn_mfma_f32_16x16x32_bf16(ah0, bl[ct][0], d, 0, 0, 0);
                d = __builtin_amdgcn_mfma_f32_16x16x32_bf16(ah1, bl[ct][1], d, 0, 0, 0);
                d = __builtin_amdgcn_mfma_f32_16x16x32_bf16(al0, bh[ct][0], d, 0, 0, 0);
                d = __builtin_amdgcn_mfma_f32_16x16x32_bf16(al1, bh[ct][1], d, 0, 0, 0);
                #pragma unroll
                for (int rr = 0; rr < 4; ++rr)
                    accr[rt][ct][rr] += exp2f(fminf(d[rr] + sav[rr] + sbv[ct], 50.f));
            }
        }
    }
    #pragma unroll
    for (int rt = 0; rt < 4; ++rt)
        #pragma unroll
        for (int ct = 0; ct < 4; ++ct)
            #pragma unroll
            for (int rr = 0; rr < 4; ++rr) {
                int row = m0 + 64 * wr + 16 * rt + (lane >> 4) * 4 + rr;
                int col = p0 + 64 * wc + 16 * ct + (lane & 15);
                unsafeAtomicAdd(&acc[row * MI + col], accr[rt][ct][rr]);
            }
}

__global__ __launch_bounds__(256) void k_psi2(const float* __restrict__ Zg, const float* __restrict__ kvar,
                                              const float* __restrict__ klen, const float* __restrict__ lvar,
                                              const float* __restrict__ acc, float* __restrict__ psi2,
                                              float* __restrict__ Kuu, float* __restrict__ G) {
    __shared__ float zi[D60];
    const int i = blockIdx.x, j = threadIdx.x;
    if (j < D60) zi[j] = Zg[i * D60 + j];
    __syncthreads();
    const float sf2 = kvar[0];
    const float l = klen[0];
    const float l2 = l * l;
    const float sigma2 = lvar[0];
    float zz = 0.f;
    #pragma unroll 10
    for (int d = 0; d < D60; ++d) {
        float dz = zi[d] - Zg[j * D60 + d];
        zz += dz * dz;
    }
    float accv = acc[i * MI + j];
    float p2 = sf2 * sf2 * __expf(-zz / (4.f * l2)) * accv;
    psi2[i * MI + j] = p2;
    float kv = sf2 * __expf(-0.5f * zz / l2) + ((i == j) ? JITTER : 0.f);
    Kuu[i * MI + j] = kv;
    G[i * MI + j] = kv + p2 / sigma2;
}

__global__ void k_reduce_r(const float* __restrict__ rpart, float* __restrict__ r) {
    int idx = blockIdx.x * blockDim.x + threadIdx.x;   // 0..1535
    float s = 0.f;
    for (int b = 0; b < 512; ++b) s += rpart[b * 1536 + idx];
    r[idx] = s;
}

// single-block panel Cholesky (in-place lower), writes 2*sum(log diag). Pivot clamped (NaN-proof).
__global__ __launch_bounds__(1024) void k_chol(float* __restrict__ A, float* __restrict__ ldout) {
    __shared__ float Pt[32][MI];   // Pt[c][r] = A[p+r][p+c]
    __shared__ float red[16];
    const int t = threadIdx.x;
    for (int p = 0; p < MI; p += 32) {
        const int R = MI - p;
        for (int idx = t; idx < R * 32; idx += 1024) {
            int c = idx / R, rr = idx % R;
            Pt[c][rr] = A[(p + rr) * MI + (p + c)];
        }
        __syncthreads();
        for (int jj = 0; jj < 32; ++jj) {
            float dg = sqrtf(fmaxf(Pt[jj][jj], 1e-20f));
            float inv = 1.0f / dg;
            for (int rr = jj + 1 + t; rr < R; rr += 1024) Pt[jj][rr] *= inv;
            if (t == 0) Pt[jj][jj] = dg;
            __syncthreads();
            int ncols = 31 - jj;
            if (ncols > 0) {
                int rows = R - jj - 1;
                for (int idx = t; idx < rows * ncols; idx += 1024) {
                    int c = jj + 1 + idx / rows;
                    int rr = jj + 1 + idx % rows;
                    Pt[c][rr] -= Pt[jj][rr] * Pt[jj][c];
                }
            }
            __syncthreads();
        }
        for (int idx = t; idx < R * 32; idx += 1024) {
            int c = idx / R, rr = idx % R;
            A[(p + rr) * MI + (p + c)] = Pt[c][rr];
        }
        const int T = R - 32;
        if (T > 0) {
            const int BT = T >> 2;
            const int nb = BT * (BT + 1) / 2;
            for (int b = t; b < nb; b += 1024) {
                int br = (int)((sqrtf(8.0f * b + 1.0f) - 1.0f) * 0.5f);
                while ((br + 1) * (br + 2) / 2 <= b) ++br;
                while (br * (br + 1) / 2 > b) --br;
                int bc = b - br * (br + 1) / 2;
                int r0 = 32 + br * 4, c0 = 32 + bc * 4;
                float s[4][4];
                #pragma unroll
                for (int i = 0; i < 4; ++i)
                    #pragma unroll
                    for (int j = 0; j < 4; ++j) s[i][j] = 0.f;
                #pragma unroll 8
                for (int kk = 0; kk < 32; ++kk) {
                    float4 av = *(const float4*)(&Pt[kk][r0]);
                    float4 bv = *(const float4*)(&Pt[kk][c0]);
                    float aa[4] = {av.x, av.y, av.z, av.w};
                    float bb[4] = {bv.x, bv.y, bv.z, bv.w};
                    #pragma unroll
                    for (int i = 0; i < 4; ++i)
                        #pragma unroll
                        for (int j = 0; j < 4; ++j) s[i][j] += aa[i] * bb[j];
                }
                #pragma unroll
                for (int i = 0; i < 4; ++i)
                    #pragma unroll
                    for (int j = 0; j < 4; ++j)
                        A[(p + r0 + i) * MI + (p + c0 + j)] -= s[i][j];
            }
        }
        __syncthreads();
    }
    float lg = 0.f;
    if (t < MI) lg = __logf(A[t * MI + t]);
    #pragma unroll
    for (int o = 32; o; o >>= 1) lg += __shfl_down(lg, o);
    if ((t & 63) == 0) red[t >> 6] = lg;
    __syncthreads();
    if (t == 0) {
        float s = 0.f;
        for (int k = 0; k < 16; ++k) s += red[k];
        ldout[0] = 2.0f * s;
    }
}

// explicit lower-triangular inverse, 16x16-blocked wavefront, single block.
// Ti must be pre-zeroed; writes diag+lower blocks of L^{-1}.
__global__ __launch_bounds__(1024) void k_trinv(const float* __restrict__ L, float* __restrict__ Ti) {
    __shared__ float Dinv[16][16][16];   // 16 KB
    __shared__ float AccSh[16][16][16];  // 16 KB
    const int t = threadIdx.x;
    if (t < 256) {
        const int blk = t >> 4, col = t & 15;
        float x[16];
        #pragma unroll
        for (int rr = 0; rr < 16; ++rr) {
            float s = (rr == col) ? 1.f : 0.f;
            #pragma unroll
            for (int j = 0; j < 16; ++j)
                if (j >= col && j < rr) s -= L[(blk * 16 + rr) * MI + blk * 16 + j] * x[j];
            x[rr] = (rr >= col) ? s / L[(blk * 16 + rr) * MI + blk * 16 + rr] : 0.f;
        }
        #pragma unroll
        for (int rr = 0; rr < 16; ++rr) Dinv[blk][rr][col] = x[rr];
    }
    __syncthreads();
    for (int idx = t; idx < 16 * 16 * 16; idx += 1024) {
        int blk = idx >> 8, rr = (idx >> 4) & 15, c = idx & 15;
        Ti[(blk * 16 + rr) * MI + blk * 16 + c] = Dinv[blk][rr][c];
    }
    const int g = t >> 6, lane = t & 63;
    const int c = lane & 15, r0 = (lane >> 4) * 4;
    for (int s = 1; s <= 15; ++s) {
        const int j = g, i = g + s;
        __syncthreads();
        float a4[4] = {0.f, 0.f, 0.f, 0.f};
        if (i < 16) {
            for (int kb = j; kb < i; ++kb) {
                #pragma unroll 4
                for (int kk = 0; kk < 16; ++kk) {
                    float tv = Ti[(kb * 16 + kk) * MI + j * 16 + c];
                    #pragma unroll
                    for (int rr = 0; rr < 4; ++rr)
                        a4[rr] -= L[(i * 16 + r0 + rr) * MI + kb * 16 + kk] * tv;
                }
            }
            #pragma unroll
            for (int rr = 0; rr < 4; ++rr) AccSh[g][r0 + rr][c] = a4[rr];
        }
        __syncthreads();
        if (i < 16) {
            float o4[4] = {0.f, 0.f, 0.f, 0.f};
            #pragma unroll
            for (int kk = 0; kk < 16; ++kk) {
                float av = AccSh[g][kk][c];
                #pragma unroll
                for (int rr = 0; rr < 4; ++rr)
                    o4[rr] += Dinv[i][r0 + rr][kk] * av;
            }
            #pragma unroll
            for (int rr = 0; rr < 4; ++rr)
                Ti[(i * 16 + r0 + rr) * MI + j * 16 + c] = o4[rr];
        }
    }
}

// trace(Kuu^{-1} psi2) = sum_k v_k^T psi2 v_k, v_k = row k of Linv
__global__ __launch_bounds__(256) void k_tracedot(const float* __restrict__ Ti, const float* __restrict__ psi2,
                                                  float* __restrict__ scal) {
    __shared__ float vsh[MI];
    __shared__ float red[4];
    const int k = blockIdx.x, t = threadIdx.x;
    vsh[t] = Ti[k * MI + t];
    __syncthreads();
    float vj = vsh[t];
    float s = 0.f;
    for (int i = 0; i <= k; ++i) s += vsh[i] * psi2[i * MI + t];
    s *= vj;
    #pragma unroll
    for (int o = 32; o; o >>= 1) s += __shfl_down(s, o);
    if ((t & 63) == 0) red[t >> 6] = s;
    __syncthreads();
    if (t == 0) unsafeAtomicAdd(&scal[4], red[0] + red[1] + red[2] + red[3]);
}

// csum = sum_q || LG^{-1} r_q ||^2 ; assemble final bound
__global__ __launch_bounds__(256) void k_final(const float* __restrict__ LGi, const float* __restrict__ r,
                                               const float* __restrict__ scal,
                                               const float* __restrict__ kvar,
                                               const float* __restrict__ lvar, const int* __restrict__ ltp,
                                               float* __restrict__ out) {
    const int t = threadIdx.x;
    __shared__ float red[4];
    float y[QD] = {0.f, 0.f, 0.f, 0.f, 0.f, 0.f};
    for (int j = 0; j <= t; ++j) {
        float lv = LGi[t * MI + j];
        #pragma unroll
        for (int q = 0; q < QD; ++q) y[q] += lv * r[j * QD + q];
    }
    float cs = 0.f;
    #pragma unroll
    for (int q = 0; q < QD; ++q) cs += y[q] * y[q];
    #pragma unroll
    for (int o = 32; o; o >>= 1) cs += __shfl_down(cs, o);
    if ((t & 63) == 0) red[t >> 6] = cs;
    __syncthreads();
    if (t == 0) {
        double csum = (double)red[0] + red[1] + red[2] + red[3];
        double sigma2 = (double)lvar[0];
        double sf2 = (double)kvar[0];
        double two_pi = 6.283185307179586;
        double Nw = (double)NW, Q = (double)QD;
        double psi0 = Nw * sf2;
        double trace_AAT = (double)scal[4] / sigma2;
        double logdetB = (double)scal[6] - (double)scal[5];
        double bound = -0.5 * Nw * Q * log(two_pi * sigma2);
        bound += -0.5 / sigma2 * ((double)scal[0] + (double)scal[1]);
        bound += -0.5 * Q * (psi0 / sigma2 - trace_AAT);
        bound += -0.5 * Q * logdetB;
        bound += 0.5 * csum / (sigma2 * sigma2);
        bound += 0.5 * (double)scal[2] + Nw * Q * 0.5 * log(two_pi);
        bound += -(double)ltp[0] * Q * log(two_pi) - 0.5 * (double)scal[3];
        out[0] = (float)bound;
    }
}

extern "C" void kernel_launch(void* const* d_in, const int* in_sizes, int n_in,
                              void* d_out, int out_size, void* d_ws, size_t ws_size,
                              hipStream_t stream) {
    (void)in_sizes; (void)n_in; (void)out_size; (void)ws_size;
    const float* Xm = (const float*)d_in[0];
    const float* Xv = (const float*)d_in[1];
    const float* Zg = (const float*)d_in[2];
    const float* kvar = (const float*)d_in[3];
    const float* klen = (const float*)d_in[4];
    const float* lvar = (const float*)d_in[5];
    const int* ltp = (const int*)d_in[6];
    float* ws = (float*)d_ws;
    float* W = ws + OFF_W;
    float* Slog = ws + OFF_SLOG;
    float* acc = ws + OFF_ACC;
    float* Kuu = ws + OFF_KUU;
    float* G = ws + OFF_G;
    float* psi2 = ws + OFF_PSI2;
    float* rpart = ws + OFF_RPART;
    float* r = ws + OFF_R;
    float* scal = ws + OFF_SCAL;
    float* Ti1 = ws + OFF_TI1;
    float* Ti2 = ws + OFF_TI2;

    hipMemsetAsync(acc, 0, MI * MI * sizeof(float), stream);
    hipMemsetAsync(scal, 0, 16 * sizeof(float), stream);
    hipMemsetAsync(Ti1, 0, 2 * MI * MI * sizeof(float), stream);  // Ti1 + Ti2 contiguous

    k_reduce_x<<<64, 256, 0, stream>>>(Xm, Xv, scal);
    k_prep<<<512, 256, 0, stream>>>(Xm, Xv, Zg, kvar, klen, W, Slog, rpart);
    k_acc<<<512, 256, 0, stream>>>(Zg, W, Slog, acc);
    k_psi2<<<256, 256, 0, stream>>>(Zg, kvar, klen, lvar, acc, psi2, Kuu, G);
    k_reduce_r<<<6, 256, 0, stream>>>(rpart, r);
    k_chol<<<1, 1024, 0, stream>>>(Kuu, scal + 5);
    k_chol<<<1, 1024, 0, stream>>>(G, scal + 6);
    k_trinv<<<1, 1024, 0, stream>>>(Kuu, Ti1);
    k_trinv<<<1, 1024, 0, stream>>>(G, Ti2);
    k_tracedot<<<256, 256, 0, stream>>>(Ti1, psi2, scal);
    k_final<<<1, 256, 0, stream>>>(Ti2, r, scal, kvar, lvar, ltp, (float*)d_out);
}

// Round 4
// 813.904 us; speedup vs baseline: 2.1325x; 1.6015x over previous
//
#include <hip/hip_runtime.h>
#include <math.h>

#define QD 6
#define LTC 10
#define NW 8192
#define NT (NW + LTC)      // 8202
#define D60 60
#define MI 256
#define JITTER 1e-6f
#define LOG2E 1.4426950408889634f

typedef __attribute__((ext_vector_type(8))) short bf16x8;
typedef __attribute__((ext_vector_type(4))) float f32x4;

// ws layout (float offsets)
#define OFF_W      0                       // 8192*64
#define OFF_SLOG   524288                  // 8192*256 (reused post-k_acc: KT/GT)
#define OFF_ACC    (OFF_SLOG + 2097152)    // 65536
#define OFF_KUU    (OFF_ACC + 65536)
#define OFF_G      (OFF_KUU + 65536)
#define OFF_PSI2   (OFF_G + 65536)
#define OFF_RPART  (OFF_PSI2 + 65536)      // 512*256*6
#define OFF_R      (OFF_RPART + 786432)    // 1536
#define OFF_SCAL   (OFF_R + 1536)          // 16
#define OFF_TI1    (OFF_SCAL + 16)         // 65536
// aliases into dead Slog region (only used after k_acc completes):
#define OFF_KT     OFF_SLOG                // 65536
#define OFF_GT     (OFF_SLOG + 65536)      // 65536
// scal: 0 sumXvo, 1 sumXmo2, 2 sumlogXvo, 3 summb, 4 trace_raw, 5 ldK, 6 ldG

__device__ __forceinline__ ushort f2bf(float f) {
    union { float f; unsigned u; } x; x.f = f;
    unsigned r = x.u + 0x7fffu + ((x.u >> 16) & 1u);
    return (ushort)(r >> 16);
}
__device__ __forceinline__ float bf2f(ushort h) {
    return __uint_as_float(((unsigned)h) << 16);
}
__device__ __forceinline__ unsigned cvt_pk_bf16(float a, float b) {
    unsigned r;
    asm("v_cvt_pk_bf16_f32 %0, %1, %2" : "=v"(r) : "v"(a), "v"(b));
    return r;   // lo16 = bf16(a), hi16 = bf16(b), RNE
}

__global__ __launch_bounds__(256) void k_reduce_x(const float* __restrict__ Xm,
                                                  const float* __restrict__ Xv,
                                                  float* __restrict__ scal) {
    float s0 = 0.f, s1 = 0.f, s2 = 0.f, s3 = 0.f;
    const int tot = NT * QD;
    for (int i = blockIdx.x * blockDim.x + threadIdx.x; i < tot; i += gridDim.x * blockDim.x) {
        float xm = Xm[i], xv = Xv[i];
        if (i >= LTC * QD) { s0 += xv; s1 += xm * xm; s2 += __logf(xv); }
        else { s3 += xm * xm + xv; }
    }
    #pragma unroll
    for (int o = 32; o; o >>= 1) {
        s0 += __shfl_down(s0, o); s1 += __shfl_down(s1, o);
        s2 += __shfl_down(s2, o); s3 += __shfl_down(s3, o);
    }
    __shared__ float red[4][4];
    const int t = threadIdx.x;
    if ((t & 63) == 0) { int w = t >> 6; red[0][w] = s0; red[1][w] = s1; red[2][w] = s2; red[3][w] = s3; }
    __syncthreads();
    if (t == 0) {
        float a0 = 0, a1 = 0, a2 = 0, a3 = 0;
        for (int w = 0; w < 4; ++w) { a0 += red[0][w]; a1 += red[1][w]; a2 += red[2][w]; a3 += red[3][w]; }
        unsafeAtomicAdd(&scal[0], a0); unsafeAtomicAdd(&scal[1], a1);
        unsafeAtomicAdd(&scal[2], a2); unsafeAtomicAdd(&scal[3], a3);
    }
}

// prep: per-n scaled w (-0.5*log2e*w, zeros at 60..63), Slog, psi1^T X_mo partials
__global__ __launch_bounds__(256) void k_prep(const float* __restrict__ Xm, const float* __restrict__ Xv,
                                              const float* __restrict__ Zg, const float* __restrict__ kvar,
                                              const float* __restrict__ klen,
                                              float* __restrict__ W, float* __restrict__ Slog,
                                              float* __restrict__ rpart) {
    __shared__ float Zt[D60][MI];
    __shared__ float4 quad[D60];   // {w*mu, w, 1/(S+l2), mu}
    __shared__ float ldsm[66];
    __shared__ float ldss[60];
    __shared__ float sld[2];       // 0: ld1, 1: base=0.5*(ld2-e1)
    const int t = threadIdx.x;
    const float sf2 = kvar[0];
    const float l = klen[0];
    const float l2 = l * l;
    for (int idx = t; idx < D60 * MI; idx += 256) {
        int d = idx >> 8, m = idx & 255;
        Zt[d][m] = Zg[m * D60 + d];
    }
    float r6[QD];
    #pragma unroll
    for (int q = 0; q < QD; ++q) r6[q] = 0.f;
    const int n0 = blockIdx.x * 16;
    for (int nn = 0; nn < 16; ++nn) {
        const int n = n0 + nn;
        __syncthreads();
        if (t < 66) ldsm[t] = Xm[n * QD + t];
        if (t >= 128 && t < 188) ldss[t - 128] = Xv[n * QD + (t - 128)];
        __syncthreads();
        if (t < 64) {
            float lt1 = 0.f, lt2 = 0.f, e1t = 0.f;
            if (t < 60) {
                float S = ldss[t], mu = ldsm[t];
                float w = 1.0f / (2.0f * S + l2);
                float invd1 = 1.0f / (S + l2);
                quad[t] = make_float4(w * mu, w, invd1, mu);
                W[n * 64 + t] = -0.5f * LOG2E * w;
                lt1 = __logf(1.0f + S / l2);
                lt2 = __logf(1.0f + 2.0f * S / l2);
                e1t = w * mu * mu;
            } else {
                W[n * 64 + t] = 0.f;
            }
            #pragma unroll
            for (int o = 32; o; o >>= 1) {
                lt1 += __shfl_down(lt1, o); lt2 += __shfl_down(lt2, o); e1t += __shfl_down(e1t, o);
            }
            if (t == 0) { sld[0] = -0.5f * lt1; sld[1] = 0.5f * (-0.5f * lt2 - e1t); }
        }
        __syncthreads();
        float e2 = 0.f, e3 = 0.f, q1 = 0.f;
        #pragma unroll 10
        for (int d = 0; d < D60; ++d) {
            float4 qd = quad[d];
            float z = Zt[d][t];
            e2 += qd.x * z;
            e3 += qd.y * z * z;
            float dm = qd.w - z;
            q1 += dm * dm * qd.z;
        }
        Slog[n * MI + t] = sld[1] + e2 - 0.25f * e3;
        float psi1 = sf2 * __expf(sld[0] - 0.5f * q1);
        #pragma unroll
        for (int q = 0; q < QD; ++q) r6[q] += psi1 * ldsm[60 + q];
    }
    #pragma unroll
    for (int q = 0; q < QD; ++q) rpart[(blockIdx.x * MI + t) * QD + q] = r6[q];
}

// main: acc[m,p] += sum_n exp2( LOG2E*(Slog_a + Slog_b) + d ), d = -LOG2E*e4 via split-bf16 MFMA
__global__ __launch_bounds__(256, 2) void k_acc(const float* __restrict__ Zg, const float* __restrict__ W,
                                                const float* __restrict__ Slog, float* __restrict__ acc) {
    __shared__ ushort Ah[128 * 64];   // 16 KB, XOR-swizzled rows
    __shared__ ushort Al[128 * 64];   // 16 KB
    __shared__ float saa[128], sbb[128];
    const int t = threadIdx.x;
    const int tile = blockIdx.x & 3;
    const int nc = blockIdx.x >> 2;      // 0..127, 64 n each
    const int m0 = (tile >> 1) * 128, p0 = (tile & 1) * 128;
    const int lane = t & 63, wid = t >> 6;
    const int wr = wid >> 1, wc = wid & 1;
    const int sm = t & 127, kh = t >> 7;

    // persistent Z rows for A staging: zr[j] = Z[(m0+sm)][kh*32+j]
    float zr[32];
    #pragma unroll
    for (int j = 0; j < 32; ++j) {
        int k = kh * 32 + j;
        zr[j] = (k < D60) ? Zg[(m0 + sm) * D60 + k] : 0.f;
    }
    // stage B hi/lo into Ah/Al temporarily, then keep fragments in registers
    for (int idx = t; idx < 128 * 64; idx += 256) {
        int p = idx >> 6, k = idx & 63;
        float v = (k < D60) ? Zg[(p0 + p) * D60 + k] : 0.f;
        ushort hi = f2bf(v);
        ushort lo = f2bf(v - bf2f(hi));
        int byte = p * 128 + ((k * 2) ^ ((p & 7) << 4));
        *(ushort*)((char*)Ah + byte) = hi;
        *(ushort*)((char*)Al + byte) = lo;
    }
    __syncthreads();
    bf16x8 bh[4][2], bl[4][2];
    #pragma unroll
    for (int ct = 0; ct < 4; ++ct) {
        int p = 64 * wc + 16 * ct + (lane & 15);
        int swz = (p & 7) << 4;
        #pragma unroll
        for (int h = 0; h < 2; ++h) {
            int byte = p * 128 + ((((lane >> 4) * 16) + 64 * h) ^ swz);
            bh[ct][h] = *(const bf16x8*)((const char*)Ah + byte);
            bl[ct][h] = *(const bf16x8*)((const char*)Al + byte);
        }
    }

    float accr[4][4][4];
    #pragma unroll
    for (int a = 0; a < 4; ++a)
        #pragma unroll
        for (int b = 0; b < 4; ++b)
            #pragma unroll
            for (int c = 0; c < 4; ++c) accr[a][b][c] = 0.f;

    const int n0 = nc * 64;
    for (int nn = 0; nn < 64; ++nn) {
        const int n = n0 + nn;
        __syncthreads();   // previous compute done reading Ah/Al
        // ---- stage A hi/lo (a = Wscaled * z, fp32 product, split to bf16 pair) ----
        {
            const float4* wp = (const float4*)(W + n * 64 + kh * 32);
            float av[32];
            #pragma unroll
            for (int j = 0; j < 8; ++j) {
                float4 f = wp[j];
                av[4 * j + 0] = f.x * zr[4 * j + 0];
                av[4 * j + 1] = f.y * zr[4 * j + 1];
                av[4 * j + 2] = f.z * zr[4 * j + 2];
                av[4 * j + 3] = f.w * zr[4 * j + 3];
            }
            unsigned pkh[16], pkl[16];
            #pragma unroll
            for (int j = 0; j < 16; ++j) {
                float v0 = av[2 * j], v1 = av[2 * j + 1];
                unsigned ph = cvt_pk_bf16(v0, v1);
                float h0 = __uint_as_float(ph << 16);
                float h1 = __uint_as_float(ph & 0xffff0000u);
                pkh[j] = ph;
                pkl[j] = cvt_pk_bf16(v0 - h0, v1 - h1);
            }
            #pragma unroll
            for (int cc = 0; cc < 4; ++cc) {
                int byte = sm * 128 + (((kh * 64) + cc * 16) ^ ((sm & 7) << 4));
                uint4 vh; vh.x = pkh[4 * cc]; vh.y = pkh[4 * cc + 1]; vh.z = pkh[4 * cc + 2]; vh.w = pkh[4 * cc + 3];
                uint4 vl; vl.x = pkl[4 * cc]; vl.y = pkl[4 * cc + 1]; vl.z = pkl[4 * cc + 2]; vl.w = pkl[4 * cc + 3];
                *(uint4*)((char*)Ah + byte) = vh;
                *(uint4*)((char*)Al + byte) = vl;
            }
            if (t < 128) saa[t] = LOG2E * Slog[n * MI + m0 + t];
            else sbb[t - 128] = LOG2E * Slog[n * MI + p0 + (t - 128)];
        }
        __syncthreads();
        // ---- compute ----
        float sbv[4];
        #pragma unroll
        for (int ct = 0; ct < 4; ++ct) sbv[ct] = sbb[64 * wc + 16 * ct + (lane & 15)];
        #pragma unroll
        for (int rt = 0; rt < 4; ++rt) {
            int m = 64 * wr + 16 * rt + (lane & 15);
            int swz = (m & 7) << 4;
            bf16x8 ah0 = *(const bf16x8*)((const char*)Ah + m * 128 + (((lane >> 4) * 16) ^ swz));
            bf16x8 ah1 = *(const bf16x8*)((const char*)Ah + m * 128 + ((64 + (lane >> 4) * 16) ^ swz));
            bf16x8 al0 = *(const bf16x8*)((const char*)Al + m * 128 + (((lane >> 4) * 16) ^ swz));
            bf16x8 al1 = *(const bf16x8*)((const char*)Al + m * 128 + ((64 + (lane >> 4) * 16) ^ swz));
            float sav[4];
            int rbase = 64 * wr + 16 * rt + (lane >> 4) * 4;
            #pragma unroll
            for (int rr = 0; rr < 4; ++rr) sav[rr] = saa[rbase + rr];
            #pragma unroll
            for (int ct = 0; ct < 4; ++ct) {
                f32x4 d = {0.f, 0.f, 0.f, 0.f};
                d = __builtin_amdgcn_mfma_f32_16x16x32_bf16(ah0, bh[ct][0], d, 0, 0, 0);
                d = __builtin_amdgcn_mfma_f32_16x16x32_bf16(ah1, bh[ct][1], d, 0, 0, 0);
                d = __builtin_amdgcn_mfma_f32_16x16x32_bf16(ah0, bl[ct][0], d, 0, 0, 0);
                d = __builtin_amdgcn_mfma_f32_16x16x32_bf16(ah1, bl[ct][1], d, 0, 0, 0);
                d = __builtin_amdgcn_mfma_f32_16x16x32_bf16(al0, bh[ct][0], d, 0, 0, 0);
                d = __builtin_amdgcn_mfma_f32_16x16x32_bf16(al1, bh[ct][1], d, 0, 0, 0);
                #pragma unroll
                for (int rr = 0; rr < 4; ++rr)
                    accr[rt][ct][rr] += exp2f(fminf(d[rr] + sav[rr] + sbv[ct], 50.f));
            }
        }
    }
    #pragma unroll
    for (int rt = 0; rt < 4; ++rt)
        #pragma unroll
        for (int ct = 0; ct < 4; ++ct)
            #pragma unroll
            for (int rr = 0; rr < 4; ++rr) {
                int row = m0 + 64 * wr + 16 * rt + (lane >> 4) * 4 + rr;
                int col = p0 + 64 * wc + 16 * ct + (lane & 15);
                unsafeAtomicAdd(&acc[row * MI + col], accr[rt][ct][rr]);
            }
}

__global__ __launch_bounds__(256) void k_psi2(const float* __restrict__ Zg, const float* __restrict__ kvar,
                                              const float* __restrict__ klen, const float* __restrict__ lvar,
                                              const float* __restrict__ acc, float* __restrict__ psi2,
                                              float* __restrict__ Kuu, float* __restrict__ G) {
    __shared__ float zi[D60];
    const int i = blockIdx.x, j = threadIdx.x;
    if (j < D60) zi[j] = Zg[i * D60 + j];
    __syncthreads();
    const float sf2 = kvar[0];
    const float l = klen[0];
    const float l2 = l * l;
    const float sigma2 = lvar[0];
    float zz = 0.f;
    #pragma unroll 10
    for (int d = 0; d < D60; ++d) {
        float dz = zi[d] - Zg[j * D60 + d];
        zz += dz * dz;
    }
    float accv = acc[i * MI + j];
    float p2 = sf2 * sf2 * __expf(-zz / (4.f * l2)) * accv;
    psi2[i * MI + j] = p2;
    float kv = sf2 * __expf(-0.5f * zz / l2) + ((i == j) ? JITTER : 0.f);
    Kuu[i * MI + j] = kv;
    G[i * MI + j] = kv + p2 / sigma2;
}

__global__ void k_reduce_r(const float* __restrict__ rpart, float* __restrict__ r) {
    int idx = blockIdx.x * blockDim.x + threadIdx.x;   // 0..1535
    float s = 0.f;
    for (int b = 0; b < 512; ++b) s += rpart[b * 1536 + idx];
    r[idx] = s;
}

// concurrent 2-matrix single-block panel Cholesky (in-place lower) + transpose output,
// writes 2*sum(log diag) to scal[5+blockIdx]. Pivot clamped (NaN-proof).
__global__ __launch_bounds__(1024) void k_chol2(float* __restrict__ A0, float* __restrict__ A1,
                                                float* __restrict__ At0, float* __restrict__ At1,
                                                float* __restrict__ scal) {
    float* A  = blockIdx.x ? A1 : A0;
    float* At = blockIdx.x ? At1 : At0;
    float* ldout = scal + 5 + blockIdx.x;
    __shared__ float Pt[32][MI];   // Pt[c][r] = A[p+r][p+c]
    __shared__ float red[16];
    const int t = threadIdx.x;
    for (int p = 0; p < MI; p += 32) {
        const int R = MI - p;
        for (int idx = t; idx < R * 32; idx += 1024) {
            int c = idx / R, rr = idx % R;
            Pt[c][rr] = A[(p + rr) * MI + (p + c)];
        }
        __syncthreads();
        for (int jj = 0; jj < 32; ++jj) {
            float dg = sqrtf(fmaxf(Pt[jj][jj], 1e-20f));
            float inv = 1.0f / dg;
            for (int rr = jj + 1 + t; rr < R; rr += 1024) Pt[jj][rr] *= inv;
            if (t == 0) Pt[jj][jj] = dg;
            __syncthreads();
            int ncols = 31 - jj;
            if (ncols > 0) {
                int rows = R - jj - 1;
                for (int idx = t; idx < rows * ncols; idx += 1024) {
                    int c = jj + 1 + idx / rows;
                    int rr = jj + 1 + idx % rows;
                    Pt[c][rr] -= Pt[jj][rr] * Pt[jj][c];
                }
            }
            __syncthreads();
        }
        for (int idx = t; idx < R * 32; idx += 1024) {
            int c = idx / R, rr = idx % R;
            float v = Pt[c][rr];
            A[(p + rr) * MI + (p + c)] = v;
            At[(p + c) * MI + (p + rr)] = v;
        }
        const int T = R - 32;
        if (T > 0) {
            const int BT = T >> 2;
            const int nb = BT * (BT + 1) / 2;
            for (int b = t; b < nb; b += 1024) {
                int br = (int)((sqrtf(8.0f * b + 1.0f) - 1.0f) * 0.5f);
                while ((br + 1) * (br + 2) / 2 <= b) ++br;
                while (br * (br + 1) / 2 > b) --br;
                int bc = b - br * (br + 1) / 2;
                int r0 = 32 + br * 4, c0 = 32 + bc * 4;
                float s[4][4];
                #pragma unroll
                for (int i = 0; i < 4; ++i)
                    #pragma unroll
                    for (int j = 0; j < 4; ++j) s[i][j] = 0.f;
                #pragma unroll 8
                for (int kk = 0; kk < 32; ++kk) {
                    float4 av = *(const float4*)(&Pt[kk][r0]);
                    float4 bv = *(const float4*)(&Pt[kk][c0]);
                    float aa[4] = {av.x, av.y, av.z, av.w};
                    float bb[4] = {bv.x, bv.y, bv.z, bv.w};
                    #pragma unroll
                    for (int i = 0; i < 4; ++i)
                        #pragma unroll
                        for (int j = 0; j < 4; ++j) s[i][j] += aa[i] * bb[j];
                }
                #pragma unroll
                for (int i = 0; i < 4; ++i)
                    #pragma unroll
                    for (int j = 0; j < 4; ++j)
                        A[(p + r0 + i) * MI + (p + c0 + j)] -= s[i][j];
            }
        }
        __syncthreads();
    }
    float lg = 0.f;
    if (t < MI) lg = __logf(A[t * MI + t]);
    #pragma unroll
    for (int o = 32; o; o >>= 1) lg += __shfl_down(lg, o);
    if ((t & 63) == 0) red[t >> 6] = lg;
    __syncthreads();
    if (t == 0) {
        float s = 0.f;
        for (int k = 0; k < 16; ++k) s += red[k];
        ldout[0] = 2.0f * s;
    }
}

// wave-parallel forward triangular solve: L x = b for NQ RHS, single 64-lane wave,
// lane owns rows 4*lane..4*lane+3. At = L^T (coalesced column access). Returns sum of x^2.
template<int NQ, bool WTI>
__device__ __forceinline__ float tri_fwd(const float* __restrict__ At, float* __restrict__ Ti,
                                         int j0, float (&acc)[4][NQ]) {
    const int lane = threadIdx.x & 63;
    const int r0 = lane * 4;
    float invd[4];
    #pragma unroll
    for (int s = 0; s < 4; ++s) invd[s] = 1.0f / At[(r0 + s) * MI + (r0 + s)];
    float4 col[4];
    #pragma unroll
    for (int s = 0; s < 4; ++s) col[s] = *(const float4*)(At + (j0 + s) * MI + r0);
    float cs = 0.f;
    for (int i4 = j0; i4 < MI; i4 += 4) {
        float4 ncol[4];
        const bool more = (i4 + 4 < MI);
        #pragma unroll
        for (int s = 0; s < 4; ++s)
            ncol[s] = more ? *(const float4*)(At + (i4 + 4 + s) * MI + r0)
                           : make_float4(0.f, 0.f, 0.f, 0.f);
        #pragma unroll
        for (int S = 0; S < 4; ++S) {
            const int i = i4 + S;
            const int src = i >> 2;
            float xi[NQ];
            #pragma unroll
            for (int q = 0; q < NQ; ++q)
                xi[q] = __shfl(acc[S][q] * invd[S], src);
            if (WTI) {
                if (lane == src) {
                    #pragma unroll
                    for (int q = 0; q < NQ; ++q) Ti[i * MI + j0 + q] = xi[q];
                }
            }
            const float lv0 = col[S].x, lv1 = col[S].y, lv2 = col[S].z, lv3 = col[S].w;
            #pragma unroll
            for (int q = 0; q < NQ; ++q) {
                acc[0][q] -= lv0 * xi[q];
                acc[1][q] -= lv1 * xi[q];
                acc[2][q] -= lv2 * xi[q];
                acc[3][q] -= lv3 * xi[q];
                cs += xi[q] * xi[q];
            }
        }
        #pragma unroll
        for (int s = 0; s < 4; ++s) col[s] = ncol[s];
    }
    return cs;
}

// L^{-1} for Kuu: 16 blocks x 16 columns each. Ti pre-zeroed.
__global__ __launch_bounds__(64) void k_trinvK(const float* __restrict__ At, float* __restrict__ Ti) {
    const int lane = threadIdx.x;
    const int j0 = blockIdx.x * 16;
    const int r0 = lane * 4;
    float acc[4][16];
    #pragma unroll
    for (int s = 0; s < 4; ++s)
        #pragma unroll
        for (int q = 0; q < 16; ++q)
            acc[s][q] = (r0 + s == j0 + q) ? 1.f : 0.f;
    tri_fwd<16, true>(At, Ti, j0, acc);
}

// trace(Kuu^{-1} psi2) = sum_k v_k^T psi2 v_k, v_k = row k of Linv
__global__ __launch_bounds__(256) void k_tracedot(const float* __restrict__ Ti, const float* __restrict__ psi2,
                                                  float* __restrict__ scal) {
    __shared__ float vsh[MI];
    __shared__ float red[4];
    const int k = blockIdx.x, t = threadIdx.x;
    vsh[t] = Ti[k * MI + t];
    __syncthreads();
    float vj = vsh[t];
    float s = 0.f;
    for (int i = 0; i <= k; ++i) s += vsh[i] * psi2[i * MI + t];
    s *= vj;
    #pragma unroll
    for (int o = 32; o; o >>= 1) s += __shfl_down(s, o);
    if ((t & 63) == 0) red[t >> 6] = s;
    __syncthreads();
    if (t == 0) unsafeAtomicAdd(&scal[4], red[0] + red[1] + red[2] + red[3]);
}

// csum = sum_q || LG^{-1} r_q ||^2 via wave solve; lane 0 assembles final bound
__global__ __launch_bounds__(64) void k_solveG_final(const float* __restrict__ GT, const float* __restrict__ r,
                                                     const float* __restrict__ scal,
                                                     const float* __restrict__ kvar,
                                                     const float* __restrict__ lvar, const int* __restrict__ ltp,
                                                     float* __restrict__ out) {
    const int lane = threadIdx.x;
    const int r0 = lane * 4;
    float acc[4][QD];
    #pragma unroll
    for (int s = 0; s < 4; ++s)
        #pragma unroll
        for (int q = 0; q < QD; ++q)
            acc[s][q] = r[(r0 + s) * QD + q];
    float cs = tri_fwd<QD, false>(GT, nullptr, 0, acc);
    if (lane == 0) {
        double csum = (double)cs;
        double sigma2 = (double)lvar[0];
        double sf2 = (double)kvar[0];
        double two_pi = 6.283185307179586;
        double Nw = (double)NW, Q = (double)QD;
        double psi0 = Nw * sf2;
        double trace_AAT = (double)scal[4] / sigma2;
        double logdetB = (double)scal[6] - (double)scal[5];
        double bound = -0.5 * Nw * Q * log(two_pi * sigma2);
        bound += -0.5 / sigma2 * ((double)scal[0] + (double)scal[1]);
        bound += -0.5 * Q * (psi0 / sigma2 - trace_AAT);
        bound += -0.5 * Q * logdetB;
        bound += 0.5 * csum / (sigma2 * sigma2);
        bound += 0.5 * (double)scal[2] + Nw * Q * 0.5 * log(two_pi);
        bound += -(double)ltp[0] * Q * log(two_pi) - 0.5 * (double)scal[3];
        out[0] = (float)bound;
    }
}

extern "C" void kernel_launch(void* const* d_in, const int* in_sizes, int n_in,
                              void* d_out, int out_size, void* d_ws, size_t ws_size,
                              hipStream_t stream) {
    (void)in_sizes; (void)n_in; (void)out_size; (void)ws_size;
    const float* Xm = (const float*)d_in[0];
    const float* Xv = (const float*)d_in[1];
    const float* Zg = (const float*)d_in[2];
    const float* kvar = (const float*)d_in[3];
    const float* klen = (const float*)d_in[4];
    const float* lvar = (const float*)d_in[5];
    const int* ltp = (const int*)d_in[6];
    float* ws = (float*)d_ws;
    float* W = ws + OFF_W;
    float* Slog = ws + OFF_SLOG;
    float* acc = ws + OFF_ACC;
    float* Kuu = ws + OFF_KUU;
    float* G = ws + OFF_G;
    float* psi2 = ws + OFF_PSI2;
    float* rpart = ws + OFF_RPART;
    float* r = ws + OFF_R;
    float* scal = ws + OFF_SCAL;
    float* Ti1 = ws + OFF_TI1;
    float* KT = ws + OFF_KT;
    float* GT = ws + OFF_GT;

    hipMemsetAsync(acc, 0, MI * MI * sizeof(float), stream);
    hipMemsetAsync(scal, 0, 16 * sizeof(float), stream);
    hipMemsetAsync(Ti1, 0, MI * MI * sizeof(float), stream);

    k_reduce_x<<<64, 256, 0, stream>>>(Xm, Xv, scal);
    k_prep<<<512, 256, 0, stream>>>(Xm, Xv, Zg, kvar, klen, W, Slog, rpart);
    k_acc<<<512, 256, 0, stream>>>(Zg, W, Slog, acc);
    k_psi2<<<256, 256, 0, stream>>>(Zg, kvar, klen, lvar, acc, psi2, Kuu, G);
    k_reduce_r<<<6, 256, 0, stream>>>(rpart, r);
    k_chol2<<<2, 1024, 0, stream>>>(Kuu, G, KT, GT, scal);
    k_trinvK<<<16, 64, 0, stream>>>(KT, Ti1);
    k_tracedot<<<256, 256, 0, stream>>>(Ti1, psi2, scal);
    k_solveG_final<<<1, 64, 0, stream>>>(GT, r, scal, kvar, lvar, ltp, (float*)d_out);
}